// Round 3
// baseline (386.795 us; speedup 1.0000x reference)
//
#include <hip/hip_runtime.h>
#include <hip/hip_bf16.h>

#define NB 8
#define PP 256
#define CC 128

typedef __attribute__((ext_vector_type(8))) unsigned short ushort8;

__device__ __forceinline__ float bf2f(unsigned short u) {
    union { unsigned int i; float f; } x; x.i = ((unsigned int)u) << 16; return x.f;
}
__device__ __forceinline__ unsigned short f2bf(float f) {
    union { float f; unsigned int i; } x; x.f = f;
    unsigned int r = x.i + 0x7fffu + ((x.i >> 16) & 1u);  // RNE
    return (unsigned short)(r >> 16);
}

// out[r][j] = sum_t X[r][t] * W1[t][j]   (X, W1 stored (in,out) row-major, fp32)
__global__ void fuse_w_kernel(const float* __restrict__ X,
                              const float* __restrict__ W1,
                              float* __restrict__ out) {
    int r = blockIdx.x, j = threadIdx.x;
    __shared__ float xr[CC];
    xr[j] = X[r * CC + j];
    __syncthreads();
    float s = 0.f;
#pragma unroll 4
    for (int t = 0; t < CC; ++t) s += xr[t] * W1[t * CC + j];
    out[r * CC + j] = s;
}

// bvec[j] = b1[j] + sum_c bp2[c] * W1[c][j]
__global__ void bvec_kernel(const float* __restrict__ b1,
                            const float* __restrict__ bp2,
                            const float* __restrict__ W1,
                            float* __restrict__ bvec) {
    int j = threadIdx.x;
    float s = b1[j];
    for (int c = 0; c < CC; ++c)
        s += bp2[c] * W1[c * CC + j];
    bvec[j] = s;
}

// row-wise projections: qw = x@Wq1, kw = x@Wk1, v = x@Wv (all fp32)
__global__ void qkv_kernel(const float* __restrict__ x,
                           const float* __restrict__ Wq1,
                           const float* __restrict__ Wk1,
                           const float* __restrict__ Wv,
                           float* __restrict__ qw, float* __restrict__ kw,
                           float* __restrict__ v) {
    int row = blockIdx.x, which = blockIdx.y, j = threadIdx.x;
    __shared__ float xr[CC];
    xr[j] = x[row * CC + j];
    __syncthreads();
    float s = 0.f;
    if (which == 0) {
#pragma unroll 4
        for (int c = 0; c < CC; ++c) s += xr[c] * Wq1[c * CC + j];
        qw[row * CC + j] = s;
    } else if (which == 1) {
#pragma unroll 4
        for (int c = 0; c < CC; ++c) s += xr[c] * Wk1[c * CC + j];
        kw[row * CC + j] = s;
    } else {
#pragma unroll 4
        for (int c = 0; c < CC; ++c) s += xr[c] * Wv[c * CC + j];
        v[row * CC + j] = s;
    }
}

// One block per (n,a): logits over all b via GEMM relu(h)@W21 + qw[b]-kw[a]+bvec,
// then relu, dot W2, softmax over b, att@v, +x.
__global__ __launch_bounds__(256) void attn_kernel(
    const float* __restrict__ x,
    const float* __restrict__ pos,
    const float* __restrict__ Wp1,
    const float* __restrict__ bp1,
    const float* __restrict__ W2,
    const float* __restrict__ b2,
    const float* __restrict__ W21,
    const float* __restrict__ bvec,
    const float* __restrict__ qw,
    const float* __restrict__ kw,
    const float* __restrict__ v,
    float* __restrict__ out)
{
    __shared__ __attribute__((aligned(16))) unsigned short Bs[CC][CC]; // W21[k][j] bf16
    __shared__ __attribute__((aligned(16))) unsigned short As[CC][CC]; // rh[k][b_local] bf16
    __shared__ float p0s[PP], p1s[PP];          // pos row; p1s reused as avpart later
    __shared__ float wa[CC], wb[CC], bpv[CC], w2s[CC], bvs[CC], kwa[CC];
    __shared__ float logits[PP];                // raw logits, then att weights

    const int t = threadIdx.x;
    const int n = blockIdx.x >> 8, a = blockIdx.x & 255;
    const int tx = t & 15, ty = t >> 4;

    if (t < CC) {
        wa[t]  = Wp1[t];
        wb[t]  = Wp1[CC + t];
        bpv[t] = bp1[t];
        w2s[t] = W2[t];
        bvs[t] = bvec[t];
        kwa[t] = kw[(n * PP + a) * CC + t];
    }
    {
        const float2* pr = (const float2*)(pos + (size_t)(n * PP + a) * PP * 2);
        float2 pp = pr[t];
        p0s[t] = pp.x;
        p1s[t] = pp.y;
    }
#pragma unroll 4
    for (int i = 0; i < 64; ++i) {
        int idx = i * 256 + t;
        ((unsigned short*)Bs)[idx] = f2bf(W21[idx]);
    }
    const float b2f = b2[0];

    for (int chunk = 0; chunk < 2; ++chunk) {
        __syncthreads();  // staging above / previous k-loop reads of As done
        // stage As: rh[k][b_local] = relu(p0*wa[k] + p1*wb[k] + bp1[k])
#pragma unroll 4
        for (int i = 0; i < 64; ++i) {
            int idx = i * 256 + t;
            int k = idx >> 7, b = idx & 127;
            int bg = chunk * 128 + b;
            float h = fmaf(p0s[bg], wa[k], fmaf(p1s[bg], wb[k], bpv[k]));
            ((unsigned short*)As)[k * CC + b] = f2bf(fmaxf(h, 0.f));
        }
        __syncthreads();

        float acc[8][8];
#pragma unroll
        for (int i = 0; i < 8; ++i)
#pragma unroll
            for (int j = 0; j < 8; ++j) acc[i][j] = 0.f;

#pragma unroll 2
        for (int k = 0; k < CC; ++k) {
            ushort8 avv = *(const ushort8*)&As[k][ty * 8];
            ushort8 bvv = *(const ushort8*)&Bs[k][tx * 8];
            float af[8], bf[8];
#pragma unroll
            for (int i = 0; i < 8; ++i) { af[i] = bf2f(avv[i]); bf[i] = bf2f(bvv[i]); }
#pragma unroll
            for (int i = 0; i < 8; ++i)
#pragma unroll
                for (int j = 0; j < 8; ++j)
                    acc[i][j] = fmaf(af[i], bf[j], acc[i][j]);
        }

        // epilogue: add qw[b]-kw[a]+bvec, relu, dot W2 -> partial logit per b
        float plog[8];
#pragma unroll
        for (int i = 0; i < 8; ++i) {
            int b = chunk * 128 + ty * 8 + i;
            const float4* qp = (const float4*)&qw[(size_t)(n * PP + b) * CC + tx * 8];
            float4 q0 = qp[0], q1 = qp[1];
            float qv[8] = {q0.x, q0.y, q0.z, q0.w, q1.x, q1.y, q1.z, q1.w};
            float s = 0.f;
#pragma unroll
            for (int j = 0; j < 8; ++j) {
                int jj = tx * 8 + j;
                float sc = acc[i][j] + qv[j] - kwa[jj] + bvs[jj];
                sc = fmaxf(sc, 0.f);
                s = fmaf(sc, w2s[jj], s);
            }
            plog[i] = s;
        }
        // reduce across the 16 tx-lanes (contiguous lanes within the wave)
#pragma unroll
        for (int i = 0; i < 8; ++i) {
            float s = plog[i];
            s += __shfl_xor(s, 1);
            s += __shfl_xor(s, 2);
            s += __shfl_xor(s, 4);
            s += __shfl_xor(s, 8);
            if (tx == 0) logits[chunk * 128 + ty * 8 + i] = s + b2f;
        }
    }
    __syncthreads();

    // ---- softmax over b (256 entries, 256 threads) ----
    float lv = logits[t];
    p0s[t] = lv;
    __syncthreads();
    for (int s = 128; s > 0; s >>= 1) {
        if (t < s) p0s[t] = fmaxf(p0s[t], p0s[t + s]);
        __syncthreads();
    }
    float m = p0s[0];
    __syncthreads();
    float e = __expf(lv - m);
    p0s[t] = e;
    __syncthreads();
    for (int s = 128; s > 0; s >>= 1) {
        if (t < s) p0s[t] += p0s[t + s];
        __syncthreads();
    }
    float denom = p0s[0];
    __syncthreads();
    logits[t] = e / denom;   // att weight
    __syncthreads();

    // ---- out[n,a,c] = x[n,a,c] + sum_b att[b] * v[n,b,c] ----
    int c = t & 127, h = t >> 7;
    const float* vp = v + (size_t)(n * PP + h * 128) * CC + c;
    float acc0 = 0.f;
#pragma unroll 4
    for (int b = 0; b < 128; ++b)
        acc0 = fmaf(logits[h * 128 + b], vp[(size_t)b * CC], acc0);
    if (h == 1) p1s[c] = acc0;
    __syncthreads();
    if (h == 0) {
        int oidx = (n * PP + a) * CC + c;
        out[oidx] = x[oidx] + acc0 + p1s[c];   // fp32 output, per reference dtype
    }
}

extern "C" void kernel_launch(void* const* d_in, const int* in_sizes, int n_in,
                              void* d_out, int out_size, void* d_ws, size_t ws_size,
                              hipStream_t stream) {
    const float* x   = (const float*)d_in[0];
    const float* pos = (const float*)d_in[1];
    const float* Wq  = (const float*)d_in[2];
    const float* Wk  = (const float*)d_in[3];
    const float* Wv  = (const float*)d_in[4];
    const float* W1  = (const float*)d_in[5];
    const float* b1  = (const float*)d_in[6];
    const float* W2  = (const float*)d_in[7];
    const float* b2  = (const float*)d_in[8];
    const float* Wp1 = (const float*)d_in[9];
    const float* bp1 = (const float*)d_in[10];
    const float* Wp2 = (const float*)d_in[11];
    const float* bp2 = (const float*)d_in[12];
    float* out = (float*)d_out;

    float* ws   = (float*)d_ws;
    float* Wq1  = ws;                 // 128*128
    float* Wk1  = Wq1 + 16384;        // 128*128
    float* W21  = Wk1 + 16384;        // 128*128
    float* bvec = W21 + 16384;        // 128
    float* qw   = bvec + 128;         // 2048*128
    float* kw   = qw + 262144;        // 2048*128
    float* v    = kw + 262144;        // 2048*128
    // total ws use: ~3.3 MB (f32)

    fuse_w_kernel<<<128, 128, 0, stream>>>(Wq, W1, Wq1);
    fuse_w_kernel<<<128, 128, 0, stream>>>(Wk, W1, Wk1);
    fuse_w_kernel<<<128, 128, 0, stream>>>(Wp2, W1, W21);
    bvec_kernel<<<1, 128, 0, stream>>>(b1, bp2, W1, bvec);
    qkv_kernel<<<dim3(2048, 3), 128, 0, stream>>>(x, Wq1, Wk1, Wv, qw, kw, v);
    attn_kernel<<<NB * PP, 256, 0, stream>>>(x, pos, Wp1, bp1, W2, b2,
                                             W21, bvec, qw, kw, v, out);
}

// Round 4
// 221.574 us; speedup vs baseline: 1.7457x; 1.7457x over previous
//
#include <hip/hip_runtime.h>
#include <hip/hip_bf16.h>

#define NB 8
#define PP 256
#define CC 128
#define APAD 136   // padded k-stride (bf16 elems): 272B row = 68 dwords = 4-bank skew

typedef __attribute__((ext_vector_type(8))) unsigned short ushort8;
typedef __bf16 bf16x8 __attribute__((ext_vector_type(8)));
typedef float float4v __attribute__((ext_vector_type(4)));

__device__ __forceinline__ unsigned short f2bf(float f) {
    union { float f; unsigned int i; } x; x.f = f;
    unsigned int r = x.i + 0x7fffu + ((x.i >> 16) & 1u);  // RNE
    return (unsigned short)(r >> 16);
}

// blocks 0..127: Wq1 = Wq@W1 (f32); 128..255: Wk1 = Wk@W1 (f32);
// 256..383: W21t[j][k] = (Wp2@W1)[k][j] in bf16; block 384: bvec.
__global__ void prep_kernel(const float* __restrict__ Wq, const float* __restrict__ Wk,
                            const float* __restrict__ Wp2, const float* __restrict__ W1,
                            const float* __restrict__ b1, const float* __restrict__ bp2,
                            float* __restrict__ Wq1, float* __restrict__ Wk1,
                            unsigned short* __restrict__ W21t, float* __restrict__ bvec) {
    int bx = blockIdx.x, j = threadIdx.x;
    __shared__ float xr[CC];
    if (bx < 384) {
        int r = bx & 127;
        const float* X = (bx < 128) ? Wq : (bx < 256) ? Wk : Wp2;
        xr[j] = X[r * CC + j];
        __syncthreads();
        float s = 0.f;
#pragma unroll 4
        for (int t = 0; t < CC; ++t) s = fmaf(xr[t], W1[t * CC + j], s);
        if (bx < 128)      Wq1[r * CC + j] = s;
        else if (bx < 256) Wk1[r * CC + j] = s;
        else               W21t[j * CC + r] = f2bf(s);   // transposed
    } else {
        float s = b1[j];
        for (int c = 0; c < CC; ++c) s = fmaf(bp2[c], W1[c * CC + j], s);
        bvec[j] = s;
    }
}

// qw = x@Wq1, kw = x@Wk1, v = x@Wv. grid (64, 3), 32 rows/block, W cached in LDS.
__global__ __launch_bounds__(256) void qkv_kernel(
    const float* __restrict__ x, const float* __restrict__ Wq1,
    const float* __restrict__ Wk1, const float* __restrict__ Wv,
    float* __restrict__ qw, float* __restrict__ kw, float* __restrict__ v) {
    __shared__ float Ws[CC * CC];
    __shared__ float xs[32 * CC];
    int t = threadIdx.x, which = blockIdx.y;
    const float* W = (which == 0) ? Wq1 : (which == 1) ? Wk1 : Wv;
    float* o = (which == 0) ? qw : (which == 1) ? kw : v;
    int row0 = blockIdx.x * 32;
#pragma unroll 8
    for (int i = 0; i < 64; ++i) Ws[i * 256 + t] = W[i * 256 + t];
#pragma unroll 8
    for (int i = 0; i < 16; ++i) xs[i * 256 + t] = x[row0 * CC + i * 256 + t];
    __syncthreads();
    int j = t & 127, rh = t >> 7;
    for (int r = rh; r < 32; r += 2) {
        float s = 0.f;
#pragma unroll 4
        for (int c = 0; c < CC; ++c) s = fmaf(xs[r * CC + c], Ws[c * CC + j], s);
        o[(row0 + r) * CC + j] = s;
    }
}

// One block per (n,a). MFMA GEMM: C[b][j] = relu(h)[b][k] @ W21[k][j], then
// logit[b] = b2 + sum_j w2[j]*relu(C + qw[b][j] + (bvec-kw[a])[j]); softmax; att@v; +x.
__global__ __launch_bounds__(256) void attn_kernel(
    const float* __restrict__ x, const float* __restrict__ pos,
    const float* __restrict__ Wp1, const float* __restrict__ bp1,
    const float* __restrict__ W2, const float* __restrict__ b2,
    const unsigned short* __restrict__ W21t, const float* __restrict__ bvec,
    const float* __restrict__ qw, const float* __restrict__ kw,
    const float* __restrict__ v, float* __restrict__ out)
{
    __shared__ __attribute__((aligned(16))) unsigned short As[128 * APAD]; // [b_loc][k]
    __shared__ __attribute__((aligned(16))) unsigned short Bs[128 * APAD]; // [j][k]
    __shared__ float p0s[PP], p1s[PP];
    __shared__ float wa[CC], wb[CC], bpv[CC], w2s[CC], kb[CC];
    __shared__ float logits[PP];
    __shared__ float avred[CC];

    const int t = threadIdx.x;
    const int n = blockIdx.x >> 8, a = blockIdx.x & 255;
    const int lane = t & 63, wv = t >> 6;
    const int ln = lane & 15, quad = lane >> 4;

    if (t < CC) {
        wa[t]  = Wp1[t];
        wb[t]  = Wp1[CC + t];
        bpv[t] = bp1[t];
        w2s[t] = W2[t];
        kb[t]  = bvec[t] - kw[(n * PP + a) * CC + t];
    }
    {
        const float2* pr = (const float2*)(pos + (size_t)(n * PP + a) * PP * 2);
        float2 pp = pr[t];
        p0s[t] = pp.x;
        p1s[t] = pp.y;
    }
    {   // stage Bs (W21 transposed, bf16): 2 threads per row
        int j = t >> 1, p = t & 1;
        const ushort8* src = (const ushort8*)(W21t + j * CC + p * 64);
        ushort8* dst = (ushort8*)(Bs + j * APAD + p * 64);
#pragma unroll
        for (int i = 0; i < 8; ++i) dst[i] = src[i];
    }
    const float b2f = b2[0];
    __syncthreads();

    // per-lane epilogue constants (col = nt*16 + ln)
    float w2v[8], kbv[8];
#pragma unroll
    for (int nt = 0; nt < 8; ++nt) { w2v[nt] = w2s[nt * 16 + ln]; kbv[nt] = kb[nt * 16 + ln]; }

    for (int chunk = 0; chunk < 2; ++chunk) {
        if (chunk) __syncthreads();   // previous k-loop's As reads done
        {   // stage As: relu(p0*wa + p1*wb + bp1), [b_loc][k] bf16
            int b = t & 127, h = t >> 7;
            float P0 = p0s[chunk * 128 + b], P1 = p1s[chunk * 128 + b];
            unsigned short* arow = As + b * APAD + h * 64;
#pragma unroll
            for (int i0 = 0; i0 < 8; ++i0) {
                ushort8 pk;
#pragma unroll
                for (int e = 0; e < 8; ++e) {
                    int k = h * 64 + i0 * 8 + e;
                    float hv = fmaf(P0, wa[k], fmaf(P1, wb[k], bpv[k]));
                    pk[e] = f2bf(fmaxf(hv, 0.f));
                }
                *(ushort8*)(arow + i0 * 8) = pk;
            }
        }
        __syncthreads();

        // wave wv: rows [wv*32, wv*32+32) of this chunk; 2 m-tiles x 8 n-tiles
        float4v acc[2][8];
#pragma unroll
        for (int i = 0; i < 2; ++i)
#pragma unroll
            for (int j = 0; j < 8; ++j) acc[i][j] = (float4v)0.f;

#pragma unroll
        for (int kk = 0; kk < 128; kk += 32) {
            const int ko = kk + quad * 8;
            bf16x8 af[2], bfr[8];
#pragma unroll
            for (int i = 0; i < 2; ++i)
                af[i] = *(const bf16x8*)(As + (wv * 32 + i * 16 + ln) * APAD + ko);
#pragma unroll
            for (int j = 0; j < 8; ++j)
                bfr[j] = *(const bf16x8*)(Bs + (j * 16 + ln) * APAD + ko);
#pragma unroll
            for (int i = 0; i < 2; ++i)
#pragma unroll
                for (int j = 0; j < 8; ++j)
                    acc[i][j] = __builtin_amdgcn_mfma_f32_16x16x32_bf16(af[i], bfr[j], acc[i][j], 0, 0, 0);
        }

        // epilogue: logit rows; D layout: row = quad*4 + r, col = nt*16 + ln
#pragma unroll
        for (int i = 0; i < 2; ++i) {
#pragma unroll
            for (int r = 0; r < 4; ++r) {
                int bl = wv * 32 + i * 16 + quad * 4 + r;
                int b = chunk * 128 + bl;
                const float* qrow = qw + (size_t)(n * PP + b) * CC;
                float s = 0.f;
#pragma unroll
                for (int nt = 0; nt < 8; ++nt) {
                    float sc = acc[i][nt][r] + qrow[nt * 16 + ln] + kbv[nt];
                    s = fmaf(fmaxf(sc, 0.f), w2v[nt], s);
                }
                s += __shfl_xor(s, 1);
                s += __shfl_xor(s, 2);
                s += __shfl_xor(s, 4);
                s += __shfl_xor(s, 8);
                if (ln == 0) logits[b] = s + b2f;
            }
        }
    }
    __syncthreads();

    // ---- softmax over 256 logits ----
    float lv = logits[t];
    p0s[t] = lv;
    __syncthreads();
    for (int s = 128; s > 0; s >>= 1) {
        if (t < s) p0s[t] = fmaxf(p0s[t], p0s[t + s]);
        __syncthreads();
    }
    float m = p0s[0];
    __syncthreads();
    float e = __expf(lv - m);
    p0s[t] = e;
    __syncthreads();
    for (int s = 128; s > 0; s >>= 1) {
        if (t < s) p0s[t] += p0s[t + s];
        __syncthreads();
    }
    float denom = p0s[0];
    __syncthreads();
    logits[t] = e / denom;
    __syncthreads();

    // ---- out[n,a,c] = x[n,a,c] + sum_b att[b] * v[n,b,c] ----
    int c = t & 127, h2 = t >> 7;
    const float* vp = v + (size_t)(n * PP + h2 * 128) * CC + c;
    float acc0 = 0.f;
#pragma unroll 4
    for (int b = 0; b < 128; ++b)
        acc0 = fmaf(logits[h2 * 128 + b], vp[(size_t)b * CC], acc0);
    if (h2 == 1) avred[c] = acc0;
    __syncthreads();
    if (h2 == 0) {
        int oidx = (n * PP + a) * CC + c;
        out[oidx] = x[oidx] + acc0 + avred[c];
    }
}

extern "C" void kernel_launch(void* const* d_in, const int* in_sizes, int n_in,
                              void* d_out, int out_size, void* d_ws, size_t ws_size,
                              hipStream_t stream) {
    const float* x   = (const float*)d_in[0];
    const float* pos = (const float*)d_in[1];
    const float* Wq  = (const float*)d_in[2];
    const float* Wk  = (const float*)d_in[3];
    const float* Wv  = (const float*)d_in[4];
    const float* W1  = (const float*)d_in[5];
    const float* b1  = (const float*)d_in[6];
    const float* W2  = (const float*)d_in[7];
    const float* b2  = (const float*)d_in[8];
    const float* Wp1 = (const float*)d_in[9];
    const float* bp1 = (const float*)d_in[10];
    const float* Wp2 = (const float*)d_in[11];
    const float* bp2 = (const float*)d_in[12];
    float* out = (float*)d_out;

    float* ws   = (float*)d_ws;
    float* Wq1  = ws;                  // 16384 f32
    float* Wk1  = Wq1 + 16384;         // 16384 f32
    float* bvec = Wk1 + 16384;         // 128 f32
    float* qw   = bvec + 128;          // 262144 f32
    float* kw   = qw + 262144;
    float* v    = kw + 262144;
    unsigned short* W21t = (unsigned short*)(v + 262144);  // 16384 bf16

    prep_kernel<<<385, 128, 0, stream>>>(Wq, Wk, Wp2, W1, b1, bp2, Wq1, Wk1, W21t, bvec);
    qkv_kernel<<<dim3(64, 3), 256, 0, stream>>>(x, Wq1, Wk1, Wv, qw, kw, v);
    attn_kernel<<<NB * PP, 256, 0, stream>>>(x, pos, Wp1, bp1, W2, b2,
                                             W21t, bvec, qw, kw, v, out);
}

// Round 5
// 194.273 us; speedup vs baseline: 1.9910x; 1.1405x over previous
//
#include <hip/hip_runtime.h>
#include <hip/hip_bf16.h>

#define NB 8
#define PP 256
#define CC 128
#define APAD 136   // padded k-stride (bf16 elems), held constant vs R4 as control

typedef __attribute__((ext_vector_type(8))) unsigned short ushort8;
typedef __bf16 bf16x8 __attribute__((ext_vector_type(8)));
typedef float float4v __attribute__((ext_vector_type(4)));

__device__ __forceinline__ unsigned short f2bf(float f) {
    union { float f; unsigned int i; } x; x.f = f;
    unsigned int r = x.i + 0x7fffu + ((x.i >> 16) & 1u);  // RNE
    return (unsigned short)(r >> 16);
}

// blocks 0..127: Wq1 = Wq@W1 (f32); 128..255: Wk1 = Wk@W1 (f32);
// 256..383: W21t[j][k] = (Wp2@W1)[k][j] in bf16; block 384: bvec.
__global__ void prep_kernel(const float* __restrict__ Wq, const float* __restrict__ Wk,
                            const float* __restrict__ Wp2, const float* __restrict__ W1,
                            const float* __restrict__ b1, const float* __restrict__ bp2,
                            float* __restrict__ Wq1, float* __restrict__ Wk1,
                            unsigned short* __restrict__ W21t, float* __restrict__ bvec) {
    int bx = blockIdx.x, j = threadIdx.x;
    __shared__ float xr[CC];
    if (bx < 384) {
        int r = bx & 127;
        const float* X = (bx < 128) ? Wq : (bx < 256) ? Wk : Wp2;
        xr[j] = X[r * CC + j];
        __syncthreads();
        float s = 0.f;
#pragma unroll 4
        for (int t = 0; t < CC; ++t) s = fmaf(xr[t], W1[t * CC + j], s);
        if (bx < 128)      Wq1[r * CC + j] = s;
        else if (bx < 256) Wk1[r * CC + j] = s;
        else               W21t[j * CC + r] = f2bf(s);   // transposed
    } else {
        float s = b1[j];
        for (int c = 0; c < CC; ++c) s = fmaf(bp2[c], W1[c * CC + j], s);
        bvec[j] = s;
    }
}

// qw = x@Wq1, kw = x@Wk1, v = x@Wv. grid (64, 3), 32 rows/block, W cached in LDS.
__global__ __launch_bounds__(256) void qkv_kernel(
    const float* __restrict__ x, const float* __restrict__ Wq1,
    const float* __restrict__ Wk1, const float* __restrict__ Wv,
    float* __restrict__ qw, float* __restrict__ kw, float* __restrict__ v) {
    __shared__ float Ws[CC * CC];
    __shared__ float xs[32 * CC];
    int t = threadIdx.x, which = blockIdx.y;
    const float* W = (which == 0) ? Wq1 : (which == 1) ? Wk1 : Wv;
    float* o = (which == 0) ? qw : (which == 1) ? kw : v;
    int row0 = blockIdx.x * 32;
#pragma unroll 8
    for (int i = 0; i < 64; ++i) Ws[i * 256 + t] = W[i * 256 + t];
#pragma unroll 8
    for (int i = 0; i < 16; ++i) xs[i * 256 + t] = x[row0 * CC + i * 256 + t];
    __syncthreads();
    int j = t & 127, rh = t >> 7;
    for (int r = rh; r < 32; r += 2) {
        float s = 0.f;
#pragma unroll 4
        for (int c = 0; c < CC; ++c) s = fmaf(xs[r * CC + c], Ws[c * CC + j], s);
        o[(row0 + r) * CC + j] = s;
    }
}

// One block per (n,a). MFMA GEMM: C[b][j] = relu(h)[b][k] @ W21[k][j], then
// logit[b] = b2 + sum_j w2[j]*relu(C + qw[b][j] + (bvec-kw[a])[j]); softmax; att@v; +x.
__global__ __launch_bounds__(256, 2) void attn_kernel(
    const float* __restrict__ x, const float* __restrict__ pos,
    const float* __restrict__ Wp1, const float* __restrict__ bp1,
    const float* __restrict__ W2, const float* __restrict__ b2,
    const unsigned short* __restrict__ W21t, const float* __restrict__ bvec,
    const float* __restrict__ qw, const float* __restrict__ kw,
    const float* __restrict__ v, float* __restrict__ out)
{
    __shared__ __attribute__((aligned(16))) unsigned short As[128 * APAD]; // [b_loc][k]
    __shared__ __attribute__((aligned(16))) unsigned short Bs[128 * APAD]; // [j][k]
    __shared__ float p0s[PP], p1s[PP];
    __shared__ float wa[CC], wb[CC], bpv[CC];
    __shared__ float logits[PP];
    __shared__ float red[8];
    __shared__ float avred[CC];

    const int t = threadIdx.x;
    const int n = blockIdx.x >> 8, a = blockIdx.x & 255;
    const int lane = t & 63, wv = t >> 6;
    const int ln = lane & 15, quad = lane >> 4;

    if (t < CC) {
        wa[t]  = Wp1[t];
        wb[t]  = Wp1[CC + t];
        bpv[t] = bp1[t];
    }
    {
        const float2* pr = (const float2*)(pos + (size_t)(n * PP + a) * PP * 2);
        float2 pp = pr[t];
        p0s[t] = pp.x;
        p1s[t] = pp.y;
    }
    {   // stage Bs (W21 transposed, bf16): 2 threads per row
        int j = t >> 1, p = t & 1;
        const ushort8* src = (const ushort8*)(W21t + j * CC + p * 64);
        ushort8* dst = (ushort8*)(Bs + j * APAD + p * 64);
#pragma unroll
        for (int i = 0; i < 8; ++i) dst[i] = src[i];
    }
    const float b2f = b2[0];

    // per-lane epilogue constants (col j = nt*16 + ln), direct gathers (L2-hot)
    float w2v[8], kbv[8];
    {
        const float* kwrow = kw + (size_t)(n * PP + a) * CC;
#pragma unroll
        for (int nt = 0; nt < 8; ++nt) {
            int j = nt * 16 + ln;
            w2v[nt] = W2[j];
            kbv[nt] = bvec[j] - kwrow[j];
        }
    }
    __syncthreads();

    for (int chunk = 0; chunk < 2; ++chunk) {
        // 1. prefetch qw epilogue values (global, independent — drains behind compute)
        float qv[2][4][8];
#pragma unroll
        for (int i = 0; i < 2; ++i)
#pragma unroll
            for (int r = 0; r < 4; ++r) {
                int b = chunk * 128 + wv * 32 + i * 16 + quad * 4 + r;
                const float* qrow = qw + (size_t)(n * PP + b) * CC + ln;
#pragma unroll
                for (int nt = 0; nt < 8; ++nt) qv[i][r][nt] = qrow[nt * 16];
            }

        if (chunk) __syncthreads();   // previous k-loop's As reads done

        {   // 2. stage As: relu(p0*wa + p1*wb + bp1), [b_loc][k] bf16, packed cvt
            int b = t & 127, h = t >> 7;
            float P0 = p0s[chunk * 128 + b], P1 = p1s[chunk * 128 + b];
            unsigned short* arow = As + b * APAD + h * 64;
#pragma unroll
            for (int i0 = 0; i0 < 8; ++i0) {
                unsigned int pr[4];
#pragma unroll
                for (int e2 = 0; e2 < 4; ++e2) {
                    int k = h * 64 + i0 * 8 + e2 * 2;
                    float h0 = fmaxf(fmaf(P0, wa[k],     fmaf(P1, wb[k],     bpv[k])),     0.f);
                    float h1 = fmaxf(fmaf(P0, wa[k + 1], fmaf(P1, wb[k + 1], bpv[k + 1])), 0.f);
                    union { __hip_bfloat162 h2; unsigned int u; } cv;
                    cv.h2 = __float22bfloat162_rn(make_float2(h0, h1));
                    pr[e2] = cv.u;
                }
                *(uint4*)(arow + i0 * 8) = make_uint4(pr[0], pr[1], pr[2], pr[3]);
            }
        }
        __syncthreads();

        // 3. MFMA k-loop: wave wv owns rows [wv*32, wv*32+32); 2 m-tiles x 8 n-tiles
        float4v acc[2][8];
#pragma unroll
        for (int i = 0; i < 2; ++i)
#pragma unroll
            for (int j = 0; j < 8; ++j) acc[i][j] = (float4v)0.f;

#pragma unroll
        for (int kk = 0; kk < 128; kk += 32) {
            const int ko = kk + quad * 8;
            bf16x8 af[2], bfr[8];
#pragma unroll
            for (int i = 0; i < 2; ++i)
                af[i] = *(const bf16x8*)(As + (wv * 32 + i * 16 + ln) * APAD + ko);
#pragma unroll
            for (int j = 0; j < 8; ++j)
                bfr[j] = *(const bf16x8*)(Bs + (j * 16 + ln) * APAD + ko);
#pragma unroll
            for (int i = 0; i < 2; ++i)
#pragma unroll
                for (int j = 0; j < 8; ++j)
                    acc[i][j] = __builtin_amdgcn_mfma_f32_16x16x32_bf16(af[i], bfr[j], acc[i][j], 0, 0, 0);
        }

        // 4. epilogue: D row = quad*4 + r, col = nt*16 + ln; qv already in regs
#pragma unroll
        for (int i = 0; i < 2; ++i) {
#pragma unroll
            for (int r = 0; r < 4; ++r) {
                int b = chunk * 128 + wv * 32 + i * 16 + quad * 4 + r;
                float s = 0.f;
#pragma unroll
                for (int nt = 0; nt < 8; ++nt) {
                    float sc = acc[i][nt][r] + qv[i][r][nt] + kbv[nt];
                    s = fmaf(fmaxf(sc, 0.f), w2v[nt], s);
                }
                s += __shfl_xor(s, 1);
                s += __shfl_xor(s, 2);
                s += __shfl_xor(s, 4);
                s += __shfl_xor(s, 8);
                if (ln == 0) logits[b] = s + b2f;
            }
        }
    }
    __syncthreads();   // logits ready

    // ---- softmax over 256 logits: wave shfl reductions, 3 more barriers ----
    float lv = logits[t];
    float wm = lv;
#pragma unroll
    for (int d = 1; d < 64; d <<= 1) wm = fmaxf(wm, __shfl_xor(wm, d));
    if (lane == 0) red[wv] = wm;
    __syncthreads();
    float m = fmaxf(fmaxf(red[0], red[1]), fmaxf(red[2], red[3]));
    float e = __expf(lv - m);
    float es = e;
#pragma unroll
    for (int d = 1; d < 64; d <<= 1) es += __shfl_xor(es, d);
    if (lane == 0) red[4 + wv] = es;
    __syncthreads();
    float denom = red[4] + red[5] + red[6] + red[7];
    logits[t] = e / denom;
    __syncthreads();

    // ---- out[n,a,c] = x[n,a,c] + sum_b att[b] * v[n,b,c] ----
    int c = t & 127, h2 = t >> 7;
    const float* vp = v + (size_t)(n * PP + h2 * 128) * CC + c;
    float acc0 = 0.f;
#pragma unroll 8
    for (int b = 0; b < 128; ++b)
        acc0 = fmaf(logits[h2 * 128 + b], vp[(size_t)b * CC], acc0);
    if (h2 == 1) avred[c] = acc0;
    __syncthreads();
    if (h2 == 0) {
        int oidx = (n * PP + a) * CC + c;
        out[oidx] = x[oidx] + acc0 + avred[c];
    }
}

extern "C" void kernel_launch(void* const* d_in, const int* in_sizes, int n_in,
                              void* d_out, int out_size, void* d_ws, size_t ws_size,
                              hipStream_t stream) {
    const float* x   = (const float*)d_in[0];
    const float* pos = (const float*)d_in[1];
    const float* Wq  = (const float*)d_in[2];
    const float* Wk  = (const float*)d_in[3];
    const float* Wv  = (const float*)d_in[4];
    const float* W1  = (const float*)d_in[5];
    const float* b1  = (const float*)d_in[6];
    const float* W2  = (const float*)d_in[7];
    const float* b2  = (const float*)d_in[8];
    const float* Wp1 = (const float*)d_in[9];
    const float* bp1 = (const float*)d_in[10];
    const float* Wp2 = (const float*)d_in[11];
    const float* bp2 = (const float*)d_in[12];
    float* out = (float*)d_out;

    float* ws   = (float*)d_ws;
    float* Wq1  = ws;                  // 16384 f32
    float* Wk1  = Wq1 + 16384;         // 16384 f32
    float* bvec = Wk1 + 16384;         // 128 f32
    float* qw   = bvec + 128;          // 262144 f32
    float* kw   = qw + 262144;
    float* v    = kw + 262144;
    unsigned short* W21t = (unsigned short*)(v + 262144);  // 16384 bf16

    prep_kernel<<<385, 128, 0, stream>>>(Wq, Wk, Wp2, W1, b1, bp2, Wq1, Wk1, W21t, bvec);
    qkv_kernel<<<dim3(64, 3), 256, 0, stream>>>(x, Wq1, Wk1, Wv, qw, kw, v);
    attn_kernel<<<NB * PP, 256, 0, stream>>>(x, pos, Wp1, bp1, W2, b2,
                                             W21t, bvec, qw, kw, v, out);
}